// Round 2
// baseline (1959.418 us; speedup 1.0000x reference)
//
#include <hip/hip_runtime.h>

// GRU B=256,T=2000,I=23,H=128 (gate order r,z,n) + mean over T.
// 1 batch row per block, 256 blocks (1/CU). 768 threads = 12 waves.
// Lane map: kt = lane&15 (k-tile of 8 -> 16 kt lanes cover K=128),
//           gl = lane>>4, slot = wave*4+gl in [0,48), gates [slot*8,slot*8+8).
// Per-thread: 8x8 weight tile in VGPRs, 8 h-values from LDS (2x ds_read_b128),
// k-reduction via 4-level shfl_xor fold with XOR-permuted gate order (no selects):
//   acc[i] holds gate g0 + (i ^ p), p = 4*(l&1) + 2*((l>>1)&1) + ((l>>2)&1).

#define Bb 256
#define Tt 2000
#define Ii 23
#define Hh 128
#define Gg 384

__device__ __forceinline__ float fold16(const float a[8]) {
    // level 1 (xor 1): b[i] = a[i] + partner's a[i+4]  (same gate by XOR-perm)
    float b0 = a[0] + __shfl_xor(a[4], 1, 64);
    float b1 = a[1] + __shfl_xor(a[5], 1, 64);
    float b2 = a[2] + __shfl_xor(a[6], 1, 64);
    float b3 = a[3] + __shfl_xor(a[7], 1, 64);
    // level 2 (xor 2)
    float c0 = b0 + __shfl_xor(b2, 2, 64);
    float c1 = b1 + __shfl_xor(b3, 2, 64);
    // level 3 (xor 4)
    float d = c0 + __shfl_xor(c1, 4, 64);
    // level 4 (xor 8): both halves end with the full sum
    return d + __shfl_xor(d, 8, 64);
}

__global__ __launch_bounds__(768, 3)
void gru_fused(const float* __restrict__ x,     // [B,T,I]
               const float* __restrict__ W_ih,  // [3H,I]
               const float* __restrict__ W_hh,  // [3H,H]
               const float* __restrict__ b_ih,  // [3H]
               const float* __restrict__ b_hh,  // [3H]
               float* __restrict__ out)         // [B,H]
{
    const int b    = blockIdx.x;
    const int t    = threadIdx.x;
    const int wid  = t >> 6;
    const int l    = t & 63;
    const int kt   = l & 15;            // k-tile id: k in [kt*8, kt*8+8)
    const int gl   = l >> 4;
    const int slot = wid * 4 + gl;      // [0,48)
    const int g0   = slot * 8;
    const int kb   = kt * 8;
    const int p    = ((l & 1) << 2) | (l & 2) | ((l >> 2) & 1); // XOR perm
    const bool is_n = (wid >= 8);       // slots 32..47 -> gates 256..383

    __shared__ __align__(16) float h_pad[16][12];  // h[k]: row kt holds k=kt*8..+7, pad->2-way only
    __shared__ float rec[Gg];                       // folded gate sums
    __shared__ float gxn[Hh];                       // x-side proj for n gates (incl b_ih)
    __shared__ float xbuf[2][24];                   // double-buffered x_t (elem 23 = 0 pad)

    // ---- load weights, XOR-permuted gate order: wreg[i] <-> gate g0 + (i^p) ----
    float wreg[8][8];
    #pragma unroll
    for (int i = 0; i < 8; ++i) {
        const int g = g0 + (i ^ p);
        #pragma unroll
        for (int k = 0; k < 8; ++k)
            wreg[i][k] = W_hh[(size_t)g * Hh + kb + k];
    }

    // x-projection: lane kt covers x indices [xi0, xi0+xn)
    const int xi0 = (kt < 7) ? kt * 2 : 14 + (kt - 7);
    const int xn  = (kt < 7) ? 2 : 1;
    float wih[8][2];
    #pragma unroll
    for (int i = 0; i < 8; ++i) {
        const int g = g0 + (i ^ p);
        wih[i][0] = W_ih[(size_t)g * Ii + xi0];
        wih[i][1] = (xn > 1) ? W_ih[(size_t)g * Ii + xi0 + 1] : 0.0f;
    }

    // biases: added once per gate, on the kt==0 lane (where p==0 -> a[i]<->g0+i)
    float binit[8], bxinit[8];
    #pragma unroll
    for (int i = 0; i < 8; ++i) {
        const int g = g0 + i;
        binit[i]  = (kt == 0) ? (is_n ? b_hh[g] : (b_ih[g] + b_hh[g])) : 0.0f;
        bxinit[i] = (kt == 0 && is_n) ? b_ih[g] : 0.0f;
    }

    const float* xrow = x + (size_t)b * Tt * Ii;

    // ---- init ----
    if (t < 128) h_pad[t >> 3][t & 7] = 0.0f;
    if (t < 23) { xbuf[0][t] = xrow[t]; }
    if (t == 23) { xbuf[0][23] = 0.0f; xbuf[1][23] = 0.0f; }
    float acc_mean = 0.0f;
    __syncthreads();

    for (int step = 0; step < Tt; ++step) {
        // prefetch next x_t to registers (hidden under the dot)
        float xpref = 0.0f;
        if (t < 23 && step + 1 < Tt) xpref = xrow[(size_t)(step + 1) * Ii + t];

        // ---- load h tile: 8 floats via 2x float4 ----
        const float4 hA = *reinterpret_cast<const float4*>(&h_pad[kt][0]);
        const float4 hB = *reinterpret_cast<const float4*>(&h_pad[kt][4]);
        const float hv[8] = {hA.x, hA.y, hA.z, hA.w, hB.x, hB.y, hB.z, hB.w};

        // ---- recurrent 8x8 tile MACs ----
        float racc[8];
        #pragma unroll
        for (int i = 0; i < 8; ++i) racc[i] = binit[i];
        #pragma unroll
        for (int k = 0; k < 8; ++k) {
            #pragma unroll
            for (int i = 0; i < 8; ++i)
                racc[i] = fmaf(wreg[i][k], hv[k], racc[i]);
        }

        // ---- x projection (2 MACs per gate per lane) ----
        const float xa = xbuf[step & 1][xi0];
        const float xb = xbuf[step & 1][xi0 + 1];
        if (!is_n) {
            #pragma unroll
            for (int i = 0; i < 8; ++i)
                racc[i] = fmaf(wih[i][0], xa, fmaf(wih[i][1], xb, racc[i]));
        }

        // ---- fold k across the 16 kt-lanes ----
        const float rsum = fold16(racc);
        float xsum = 0.0f;
        if (is_n) {
            float xacc[8];
            #pragma unroll
            for (int i = 0; i < 8; ++i)
                xacc[i] = fmaf(wih[i][0], xa, fmaf(wih[i][1], xb, bxinit[i]));
            xsum = fold16(xacc);
        }

        // writer lanes (bit3==0): one gate each
        if ((l & 8) == 0) {
            rec[g0 + p] = rsum;
            if (is_n) gxn[g0 + p - 2 * Hh] = xsum;
        }

        // stage next x into alternate buffer
        if (t < 23 && step + 1 < Tt) xbuf[(step + 1) & 1][t] = xpref;
        __syncthreads();

        // ---- epilogue: threads 0..127 update h ----
        if (t < Hh) {
            const int j = t;
            float s_r  = rec[j];
            float s_z  = rec[Hh + j];
            float ghn  = rec[2 * Hh + j];   // recurrent n-sum incl b_hh
            float gxnv = gxn[j];            // x-side n-sum incl b_ih
            float r = 1.0f / (1.0f + __expf(-s_r));
            float z = 1.0f / (1.0f + __expf(-s_z));
            float npre = fmaf(r, ghn, gxnv);
            float n = 2.0f / (1.0f + __expf(-2.0f * npre)) - 1.0f;
            float h_old = h_pad[j >> 3][j & 7];
            float h_new = fmaf(z, h_old - n, n);
            acc_mean += h_new;
            h_pad[j >> 3][j & 7] = h_new;
        }
        __syncthreads();
    }

    if (t < Hh) out[(size_t)b * Hh + t] = acc_mean * (1.0f / Tt);
}

extern "C" void kernel_launch(void* const* d_in, const int* in_sizes, int n_in,
                              void* d_out, int out_size, void* d_ws, size_t ws_size,
                              hipStream_t stream) {
    const float* x    = (const float*)d_in[0];
    const float* W_ih = (const float*)d_in[1];
    const float* W_hh = (const float*)d_in[2];
    const float* b_ih = (const float*)d_in[3];
    const float* b_hh = (const float*)d_in[4];
    float* out = (float*)d_out;

    gru_fused<<<Bb, 768, 0, stream>>>(x, W_ih, W_hh, b_ih, b_hh, out);
}

// Round 3
// 1616.955 us; speedup vs baseline: 1.2118x; 1.2118x over previous
//
#include <hip/hip_runtime.h>

// GRU B=256,T=2000,I=23,H=128 (gate order r,z,n) + mean over T.
// 1 batch row per block, 256 blocks (1/CU). 768 threads = 12 waves.
// Lane map: kt = lane&15 (k-tile of 8 -> 16 kt lanes cover K=128),
//           gl = lane>>4, slot = wave*4+gl in [0,48), gates [slot*8,slot*8+8).
// Per-thread: 8x8 weight tile in VGPRs, 8 h-values from LDS (2x ds_read_b128).
// k-reduction: 4-level XOR fold with XOR-permuted gate order. Levels xor1,
// xor2, xor8 run on the VALU pipe via DPP (quad_perm / row_ror:8); only the
// xor4 level uses a DS-pipe shuffle. (Round 2's all-shfl fold was DS-bound.)

#define Bb 256
#define Tt 2000
#define Ii 23
#define Hh 128
#define Gg 384

template <int ctrl>
__device__ __forceinline__ float dpp_movf(float v) {
    int r = __builtin_amdgcn_update_dpp(0, __builtin_bit_cast(int, v),
                                        ctrl, 0xf, 0xf, true);
    return __builtin_bit_cast(float, r);
}

__device__ __forceinline__ float fold16(const float a[8]) {
    // level 1 (xor 1, DPP quad_perm [1,0,3,2])
    float b0 = a[0] + dpp_movf<0xB1>(a[4]);
    float b1 = a[1] + dpp_movf<0xB1>(a[5]);
    float b2 = a[2] + dpp_movf<0xB1>(a[6]);
    float b3 = a[3] + dpp_movf<0xB1>(a[7]);
    // level 2 (xor 2, DPP quad_perm [2,3,0,1])
    float c0 = b0 + dpp_movf<0x4E>(b2);
    float c1 = b1 + dpp_movf<0x4E>(b3);
    // level 3 (xor 4) — only DS-pipe hop in the fold
    float d = c0 + __shfl_xor(c1, 4, 64);
    // level 4 (xor 8, DPP row_ror:8 — symmetric within row of 16)
    return d + dpp_movf<0x128>(d);
}

__global__ __launch_bounds__(768, 3)
void gru_fused(const float* __restrict__ x,     // [B,T,I]
               const float* __restrict__ W_ih,  // [3H,I]
               const float* __restrict__ W_hh,  // [3H,H]
               const float* __restrict__ b_ih,  // [3H]
               const float* __restrict__ b_hh,  // [3H]
               float* __restrict__ out)         // [B,H]
{
    const int b    = blockIdx.x;
    const int t    = threadIdx.x;
    const int wid  = t >> 6;
    const int l    = t & 63;
    const int kt   = l & 15;            // k-tile id: k in [kt*8, kt*8+8)
    const int gl   = l >> 4;
    const int slot = wid * 4 + gl;      // [0,48)
    const int g0   = slot * 8;
    const int kb   = kt * 8;
    const int p    = ((l & 1) << 2) | (l & 2) | ((l >> 2) & 1); // XOR perm
    const bool is_n = (wid >= 8);       // slots 32..47 -> gates 256..383

    __shared__ __align__(16) float h_pad[16][12];  // row kt holds h[kt*8..+7]
    __shared__ float rec[Gg];                       // folded gate sums
    __shared__ float gxn[Hh];                       // x-side n proj (incl b_ih)
    __shared__ float xbuf[2][24];                   // double-buffered x_t

    // ---- weights, XOR-permuted gate order: wreg[i] <-> gate g0 + (i^p) ----
    float wreg[8][8];
    #pragma unroll
    for (int i = 0; i < 8; ++i) {
        const int g = g0 + (i ^ p);
        #pragma unroll
        for (int k = 0; k < 8; ++k)
            wreg[i][k] = W_hh[(size_t)g * Hh + kb + k];
    }

    // x-projection: lane kt covers x indices [xi0, xi0+xn)
    const int xi0 = (kt < 7) ? kt * 2 : 14 + (kt - 7);
    const int xn  = (kt < 7) ? 2 : 1;
    float wih[8][2];
    #pragma unroll
    for (int i = 0; i < 8; ++i) {
        const int g = g0 + (i ^ p);
        wih[i][0] = W_ih[(size_t)g * Ii + xi0];
        wih[i][1] = (xn > 1) ? W_ih[(size_t)g * Ii + xi0 + 1] : 0.0f;
    }

    // biases: added once per gate, on the kt==0 lane (where p==0)
    float binit[8], bxinit[8];
    #pragma unroll
    for (int i = 0; i < 8; ++i) {
        const int g = g0 + i;
        binit[i]  = (kt == 0) ? (is_n ? b_hh[g] : (b_ih[g] + b_hh[g])) : 0.0f;
        bxinit[i] = (kt == 0 && is_n) ? b_ih[g] : 0.0f;
    }

    const float* xrow = x + (size_t)b * Tt * Ii;

    // ---- init ----
    if (t < 128) h_pad[t >> 3][t & 7] = 0.0f;
    if (t < 23) { xbuf[0][t] = xrow[t]; }
    if (t == 23) { xbuf[0][23] = 0.0f; xbuf[1][23] = 0.0f; }
    float acc_mean = 0.0f;
    float h_reg = 0.0f;                 // epilogue threads' private h[j]
    __syncthreads();

    for (int step = 0; step < Tt; ++step) {
        // prefetch next x_t to registers (hidden under the dot)
        float xpref = 0.0f;
        if (t < 23 && step + 1 < Tt) xpref = xrow[(size_t)(step + 1) * Ii + t];

        // ---- load h tile: 8 floats via 2x float4 ----
        const float4 hA = *reinterpret_cast<const float4*>(&h_pad[kt][0]);
        const float4 hB = *reinterpret_cast<const float4*>(&h_pad[kt][4]);
        const float hv[8] = {hA.x, hA.y, hA.z, hA.w, hB.x, hB.y, hB.z, hB.w};

        // ---- recurrent 8x8 tile MACs ----
        float racc[8];
        #pragma unroll
        for (int i = 0; i < 8; ++i) racc[i] = binit[i];
        #pragma unroll
        for (int k = 0; k < 8; ++k) {
            #pragma unroll
            for (int i = 0; i < 8; ++i)
                racc[i] = fmaf(wreg[i][k], hv[k], racc[i]);
        }

        // ---- x projection (2 MACs per gate per lane) ----
        const float xa = xbuf[step & 1][xi0];
        const float xb = xbuf[step & 1][xi0 + 1];
        if (!is_n) {
            #pragma unroll
            for (int i = 0; i < 8; ++i)
                racc[i] = fmaf(wih[i][0], xa, fmaf(wih[i][1], xb, racc[i]));
        }

        // ---- fold k across the 16 kt-lanes (DPP + 1 shfl) ----
        const float rsum = fold16(racc);
        float xsum = 0.0f;
        if (is_n) {
            float xacc[8];
            #pragma unroll
            for (int i = 0; i < 8; ++i)
                xacc[i] = fmaf(wih[i][0], xa, fmaf(wih[i][1], xb, bxinit[i]));
            xsum = fold16(xacc);
        }

        // writer lanes (bit3==0): one gate each
        if ((l & 8) == 0) {
            rec[g0 + p] = rsum;
            if (is_n) gxn[g0 + p - 2 * Hh] = xsum;
        }

        // stage next x into alternate buffer
        if (t < 23 && step + 1 < Tt) xbuf[(step + 1) & 1][t] = xpref;
        __syncthreads();

        // ---- epilogue: threads 0..127 update h ----
        if (t < Hh) {
            const int j = t;
            float s_r  = rec[j];
            float s_z  = rec[Hh + j];
            float ghn  = rec[2 * Hh + j];   // recurrent n-sum incl b_hh
            float gxnv = gxn[j];            // x-side n-sum incl b_ih
            float r = 1.0f / (1.0f + __expf(-s_r));
            float z = 1.0f / (1.0f + __expf(-s_z));
            float npre = fmaf(r, ghn, gxnv);
            float n = 2.0f / (1.0f + __expf(-2.0f * npre)) - 1.0f;
            float h_new = fmaf(z, h_reg - n, n);
            acc_mean += h_new;
            h_reg = h_new;
            h_pad[j >> 3][j & 7] = h_new;
        }
        __syncthreads();
    }

    if (t < Hh) out[(size_t)b * Hh + t] = acc_mean * (1.0f / Tt);
}

extern "C" void kernel_launch(void* const* d_in, const int* in_sizes, int n_in,
                              void* d_out, int out_size, void* d_ws, size_t ws_size,
                              hipStream_t stream) {
    const float* x    = (const float*)d_in[0];
    const float* W_ih = (const float*)d_in[1];
    const float* W_hh = (const float*)d_in[2];
    const float* b_ih = (const float*)d_in[3];
    const float* b_hh = (const float*)d_in[4];
    float* out = (float*)d_out;

    gru_fused<<<Bb, 768, 0, stream>>>(x, W_ih, W_hh, b_ih, b_hh, out);
}